// Round 7
// baseline (2265.564 us; speedup 1.0000x reference)
//
#include <hip/hip_runtime.h>
#include <hip/hip_bf16.h>

#define Bb 256
#define Tt 128
#define Cc 141
#define Dd 1536
#define Hh 141
#define Gg 564
#define Gp 576
#define Nc 1152      // combined f+b gate columns (2*Gp)
#define K2p 320      // padded layer input width for layers 1-3
#define MM (Bb*Cc)   // 36096

typedef float f32x4 __attribute__((ext_vector_type(4)));
typedef short s16x8 __attribute__((ext_vector_type(8)));
typedef _Float16 h2 __attribute__((ext_vector_type(2)));
typedef _Float16 h8 __attribute__((ext_vector_type(8)));

typedef __attribute__((address_space(1))) const void GvT;
typedef __attribute__((address_space(3))) void LvT;
#define GLOAD16(g, l) __builtin_amdgcn_global_load_lds((GvT*)(g), (LvT*)(l), 16, 0, 0)

__device__ __forceinline__ short f2bf(float f){
    union { float f; unsigned u; } v; v.f = f;
    unsigned r = v.u + 0x7fffu + ((v.u >> 16) & 1u);
    return (short)(r >> 16);
}
__device__ __forceinline__ float bf2f(short s){
    union { unsigned u; float f; } v; v.u = ((unsigned)(unsigned short)s) << 16;
    return v.f;
}
__device__ __forceinline__ float fdot2(h2 a, h2 b, float c){
#if __has_builtin(__builtin_amdgcn_fdot2)
    return __builtin_amdgcn_fdot2(a, b, c, false);
#else
    return c + (float)a.x * (float)b.x + (float)a.y * (float)b.y;
#endif
}
// anti-remat: value's def becomes the asm -> compiler cannot reload it from
// global memory (round-5 diagnosis: whh weights were rematerialized per step,
// 5.8 GB/dispatch through L2 = exactly the 340 us observed)
__device__ __forceinline__ void keep_h2(h2 &v){
    union { h2 h; unsigned u; } cv; cv.h = v;
    asm volatile("" : "+v"(cv.u));
    v = cv.h;
}
__device__ __forceinline__ float sigm(float x){ return 1.f / (1.f + __expf(-x)); }
__device__ __forceinline__ float tanh_(float x){ float e = __expf(2.f * x); return 1.f - 2.f / (e + 1.f); }

// ---------------- weight convert f32 -> bf16 with zero padding -------------
__global__ __launch_bounds__(256) void convert_pad(const float* __restrict__ src,
                                                   short* __restrict__ dst,
                                                   int R, int Kin, int Rp, int Kp){
    int idx = blockIdx.x * 256 + threadIdx.x;
    if (idx >= Rp * Kp) return;
    int r = idx / Kp, k = idx - r * Kp;
    float v = (r < R && k < Kin) ? src[(size_t)r * Kin + k] : 0.f;
    dst[idx] = f2bf(v);
}

// ---------------- char gather index ----------------------------------------
__global__ __launch_bounds__(256) void build_gather(const int* __restrict__ offm,
                                                    int* __restrict__ gidx){
    int m = blockIdx.x * 256 + threadIdx.x;
    if (m >= MM) return;
    int b = m / Cc, c = m - b * Cc;
    int found = -1;
    for (int t = 0; t < Tt; t++){
        int s = offm[((size_t)(b * Tt + t)) * 2];
        int e = offm[((size_t)(b * Tt + t)) * 2 + 1];
        if (s <= c && c < e){ found = b * Tt + t; break; }
    }
    gidx[m] = found;
}

// ---------------- gather rows of tok (f32) into xg (bf16) -------------------
__global__ __launch_bounds__(256) void gather_convert(const float* __restrict__ tok,
                                                      const int* __restrict__ gidx,
                                                      short* __restrict__ xg){
    size_t idx = (size_t)blockIdx.x * 256 + threadIdx.x;
    if (idx >= (size_t)MM * 192) return;
    int m = (int)(idx / 192), c8 = (int)(idx % 192);
    int g = gidx[m];
    s16x8 o = (s16x8)0;
    if (g >= 0){
        const float* s = tok + (size_t)g * Dd + c8 * 8;
        float4 v0 = *(const float4*)s;
        float4 v1 = *(const float4*)(s + 4);
        o[0] = f2bf(v0.x); o[1] = f2bf(v0.y); o[2] = f2bf(v0.z); o[3] = f2bf(v0.w);
        o[4] = f2bf(v1.x); o[5] = f2bf(v1.y); o[6] = f2bf(v1.z); o[7] = f2bf(v1.w);
    }
    *(s16x8*)(xg + (size_t)m * Dd + c8 * 8) = o;
}

// ---------------- GEMM: C[M,N](bf16) = A[M,K] @ B[N,K]^T + bias ------------
__global__ __launch_bounds__(256, 2) void gemm128(const short* __restrict__ A,
                                                  const short* __restrict__ Bw,
                                                  const float* __restrict__ bias1,
                                                  const float* __restrict__ bias2,
                                                  int nb1, int nb2, int halfN,
                                                  short* __restrict__ Cout,
                                                  const int* __restrict__ gidx,
                                                  int K, int NT, int ldc){
    __shared__ short As[128 * 64];
    __shared__ short Bs[128 * 64];
    const int nwg = gridDim.x;
    const int id = blockIdx.x;
    const int q = nwg >> 3, r = nwg & 7;
    const int xcd = id & 7, pos = id >> 3;
    const int wg = (xcd < r ? xcd * (q + 1) : r * (q + 1) + (xcd - r) * q) + pos;
    const int m0 = (wg / NT) * 128, n0 = (wg % NT) * 128;
    const int tid = threadIdx.x, lane = tid & 63, wv = tid >> 6;
    const int wm = wv >> 1, wn = wv & 1;
    const int r16 = lane & 15, kq = lane >> 4;

    f32x4 acc[4][4] = {};

    for (int k0 = 0; k0 < K; k0 += 64){
        #pragma unroll
        for (int i = 0; i < 4; i++){
            int e = (i * 4 + wv) * 64 + lane;
            int row = e >> 3, ch = e & 7;
            int sc = ch ^ (row & 7);
            GLOAD16(A + (size_t)(m0 + row) * K + k0 + (sc << 3),
                    As + (i * 4 + wv) * 512);
        }
        #pragma unroll
        for (int i = 0; i < 4; i++){
            int e = (i * 4 + wv) * 64 + lane;
            int row = e >> 3, ch = e & 7;
            int sc = ch ^ (row & 7);
            GLOAD16(Bw + (size_t)(n0 + row) * K + k0 + (sc << 3),
                    Bs + (i * 4 + wv) * 512);
        }
        __syncthreads();
        #pragma unroll
        for (int ks = 0; ks < 2; ks++){
            s16x8 af[4], bfr[4];
            #pragma unroll
            for (int mt = 0; mt < 4; mt++){
                int row = wm * 64 + mt * 16 + r16;
                int c = (ks * 4 + kq) ^ (row & 7);
                af[mt] = *(const s16x8*)(As + row * 64 + (c << 3));
            }
            #pragma unroll
            for (int nt = 0; nt < 4; nt++){
                int row = wn * 64 + nt * 16 + r16;
                int c = (ks * 4 + kq) ^ (row & 7);
                bfr[nt] = *(const s16x8*)(Bs + row * 64 + (c << 3));
            }
            #pragma unroll
            for (int mt = 0; mt < 4; mt++)
                #pragma unroll
                for (int nt = 0; nt < 4; nt++)
                    acc[mt][nt] = __builtin_amdgcn_mfma_f32_16x16x32_bf16(af[mt], bfr[nt], acc[mt][nt], 0, 0, 0);
        }
        __syncthreads();
    }

    #pragma unroll
    for (int nt = 0; nt < 4; nt++){
        int col = n0 + wn * 64 + nt * 16 + r16;
        float bv;
        if (col < halfN) bv = (col < nb1) ? bias1[col] : 0.f;
        else             bv = (col - halfN < nb2) ? bias2[col - halfN] : 0.f;
        #pragma unroll
        for (int mt = 0; mt < 4; mt++){
            int rowb = m0 + wm * 64 + mt * 16 + kq * 4;
            #pragma unroll
            for (int rr = 0; rr < 4; rr++){
                int row = rowb + rr;
                float v = acc[mt][nt][rr] + bv;
                if (gidx && gidx[row] < 0) v = 0.f;
                Cout[(size_t)row * ldc + col] = f2bf(v);
            }
        }
    }
}

// ---------------- LSTM scan: one (batch, dir) per block --------------------
// 576 threads, thread j owns gate row j. Weights live in 72 NAMED h2 scalars
// (no array -> no SROA/promotion question) pinned by keep_h2 asm so the
// compiler cannot rematerialize the global loads per step (round-5: remat
// made the scan L2-BW-bound at exactly 340us). h broadcast from LDS via
// ds_read_b128 (h8) with static shufflevector unpack. lgkm-only barriers.
#define WREP70(X) X(0) X(1) X(2) X(3) X(4) X(5) X(6) X(7) X(8) X(9) \
    X(10) X(11) X(12) X(13) X(14) X(15) X(16) X(17) X(18) X(19) \
    X(20) X(21) X(22) X(23) X(24) X(25) X(26) X(27) X(28) X(29) \
    X(30) X(31) X(32) X(33) X(34) X(35) X(36) X(37) X(38) X(39) \
    X(40) X(41) X(42) X(43) X(44) X(45) X(46) X(47) X(48) X(49) \
    X(50) X(51) X(52) X(53) X(54) X(55) X(56) X(57) X(58) X(59) \
    X(60) X(61) X(62) X(63) X(64) X(65) X(66) X(67) X(68) X(69)
#define WDECL(i) h2 w##i;
#define WLOAD(i) { w##i.x = (_Float16)wr[2*(i)]; w##i.y = (_Float16)wr[2*(i)+1]; }
#define WKEEP(i) keep_h2(w##i);
#define DOTC(cc, wa, wb, wc_, wd) { \
    h8 hv = ((const h8*)hraw)[cc]; \
    acc0 = fdot2(wa,  __builtin_shufflevector(hv, hv, 0, 1), acc0); \
    acc1 = fdot2(wb,  __builtin_shufflevector(hv, hv, 2, 3), acc1); \
    acc0 = fdot2(wc_, __builtin_shufflevector(hv, hv, 4, 5), acc0); \
    acc1 = fdot2(wd,  __builtin_shufflevector(hv, hv, 6, 7), acc1); }

__global__ __launch_bounds__(576, 1) __attribute__((amdgpu_waves_per_eu(1)))
void lstm_scan(const short* __restrict__ xW,
               const float* __restrict__ whh_f,
               const float* __restrict__ whh_b,
               const float* __restrict__ h0l,
               const float* __restrict__ c0l,
               short* __restrict__ xout,
               float* __restrict__ hnl,
               float* __restrict__ cnl){
    const int dir = blockIdx.x & 1;
    const int b = blockIdx.x >> 1;
    const int j = threadIdx.x;
    const float* whh = dir ? whh_b : whh_f;

    __shared__ float pre[Gg];
    __shared__ _Float16 hraw[144];    // h (141) zero-padded, read as 18x h8

    const int jw = (j < Gg) ? j : 0;  // clamp so inactive threads don't fault
    const float* wr = whh + (size_t)jw * Hh;

    WREP70(WDECL) WDECL(70) WDECL(71)
    WREP70(WLOAD)
    w70.x = (_Float16)wr[140]; w70.y = (_Float16)0.f;   // row has 141 elems
    w71.x = (_Float16)0.f;     w71.y = (_Float16)0.f;   // pad to 144
    WREP70(WKEEP) WKEEP(70)

    float hcur = 0.f, ccur = 0.f;
    if (j < Hh){
        hcur = h0l[(size_t)dir * Bb * Hh + b * Hh + j];
        ccur = c0l[(size_t)dir * Bb * Hh + b * Hh + j];
    }
    if (j < 144) hraw[j] = (j < Hh) ? (_Float16)hcur : (_Float16)0.f;
    __syncthreads();

    const short* xc = xW + (size_t)b * Cc * Nc + dir * Gp + j;
    const int dt = dir ? -1 : 1;
    const int t0 = dir ? (Cc - 1) : 0;

    short xwraw = 0;
    if (j < Gg) xwraw = xc[(size_t)t0 * Nc];

    for (int t = 0; t < Cc; t++){
        int tt = dir ? (Cc - 1 - t) : t;
        short xwraw_n = 0;
        if (t + 1 < Cc && j < Gg) xwraw_n = xc[(size_t)(tt + dt) * Nc];

        if (j < Gg){
            float acc0 = 0.f, acc1 = 0.f;
            DOTC(0,  w0,  w1,  w2,  w3)
            DOTC(1,  w4,  w5,  w6,  w7)
            DOTC(2,  w8,  w9,  w10, w11)
            DOTC(3,  w12, w13, w14, w15)
            DOTC(4,  w16, w17, w18, w19)
            DOTC(5,  w20, w21, w22, w23)
            DOTC(6,  w24, w25, w26, w27)
            DOTC(7,  w28, w29, w30, w31)
            DOTC(8,  w32, w33, w34, w35)
            DOTC(9,  w36, w37, w38, w39)
            DOTC(10, w40, w41, w42, w43)
            DOTC(11, w44, w45, w46, w47)
            DOTC(12, w48, w49, w50, w51)
            DOTC(13, w52, w53, w54, w55)
            DOTC(14, w56, w57, w58, w59)
            DOTC(15, w60, w61, w62, w63)
            DOTC(16, w64, w65, w66, w67)
            DOTC(17, w68, w69, w70, w71)
            pre[j] = bf2f(xwraw) + acc0 + acc1;
        }
        asm volatile("s_waitcnt lgkmcnt(0)" ::: "memory");
        __builtin_amdgcn_s_barrier();
        if (j < Hh){
            float gi = sigm(pre[j]);
            float gf = sigm(pre[j + Hh]);
            float gg = tanh_(pre[j + 2 * Hh]);
            float go = sigm(pre[j + 3 * Hh]);
            ccur = gf * ccur + gi * gg;
            hcur = go * tanh_(ccur);
            xout[((size_t)b * Cc + tt) * K2p + dir * Hh + j] = f2bf(hcur);
            hraw[j] = (_Float16)hcur;
        }
        asm volatile("s_waitcnt lgkmcnt(0)" ::: "memory");
        __builtin_amdgcn_s_barrier();
        xwraw = xwraw_n;
    }
    if (j < Hh){
        hnl[(size_t)dir * Bb * Hh + b * Hh + j] = hcur;
        cnl[(size_t)dir * Bb * Hh + b * Hh + j] = ccur;
    }
}

// ---------------- fold head: Wc[2][320] = w2 @ w1 (f32), bc = w2@b1 + b2 ---
__global__ __launch_bounds__(384) void wc_build(const float* __restrict__ w1,
                                                const float* __restrict__ b1,
                                                const float* __restrict__ w2,
                                                const float* __restrict__ b2,
                                                float* __restrict__ Wc){
    int j = threadIdx.x;
    if (j < K2p){
        float a0 = 0.f, a1 = 0.f;
        if (j < 282){
            for (int k = 0; k < 282; k++){
                float w = w1[(size_t)k * 282 + j];
                a0 += w2[k] * w;
                a1 += w2[282 + k] * w;
            }
        }
        Wc[j] = a0;
        Wc[K2p + j] = a1;
    } else if (j < K2p + 2){
        int o = j - K2p;
        float s = b2[o];
        for (int k = 0; k < 282; k++) s += w2[(size_t)o * 282 + k] * b1[k];
        Wc[2 * K2p + o] = s;
    }
}

// ---------------- head matvec: X1,X2 = x4 @ Wc^T + bc ---------------------
__global__ __launch_bounds__(256) void head2_k(const short* __restrict__ x4,
                                               const float* __restrict__ Wc,
                                               float* __restrict__ X1,
                                               float* __restrict__ X2){
    int m = blockIdx.x * 256 + threadIdx.x;
    if (m >= MM) return;
    const short* xr = x4 + (size_t)m * K2p;
    float a0 = 0.f, a1 = 0.f;
    #pragma unroll 4
    for (int c = 0; c < 36; c++){
        s16x8 v = *(const s16x8*)(xr + c * 8);
        #pragma unroll
        for (int u = 0; u < 8; u++){
            float xv = bf2f(v[u]);
            a0 += xv * Wc[c * 8 + u];
            a1 += xv * Wc[K2p + c * 8 + u];
        }
    }
    X1[m] = a0 + Wc[2 * K2p];
    X2[m] = a1 + Wc[2 * K2p + 1];
}

extern "C" void kernel_launch(void* const* d_in, const int* in_sizes, int n_in,
                              void* d_out, int out_size, void* d_ws, size_t ws_size,
                              hipStream_t stream){
    const float* tok     = (const float*)d_in[0];
    const int*   offm    = (const int*)d_in[1];
    const float* h0      = (const float*)d_in[2];
    const float* c0      = (const float*)d_in[3];
    const float* w_lin   = (const float*)d_in[4];
    const float* b_lin   = (const float*)d_in[5];
    const float* w_ih0_f = (const float*)d_in[6];
    const float* w_ih0_b = (const float*)d_in[7];
    const float* w_ih_f  = (const float*)d_in[8];
    const float* w_ih_b  = (const float*)d_in[9];
    const float* w_hh_f  = (const float*)d_in[10];
    const float* w_hh_b  = (const float*)d_in[11];
    const float* b_f     = (const float*)d_in[12];
    const float* b_b     = (const float*)d_in[13];
    const float* w1      = (const float*)d_in[14];
    const float* b1      = (const float*)d_in[15];
    const float* w2      = (const float*)d_in[16];
    const float* b2      = (const float*)d_in[17];

    float* out = (float*)d_out;
    float* oX1 = out;
    float* oX2 = out + MM;
    float* ohn = out + 2 * MM;
    float* ocn = ohn + 8 * Bb * Hh;

    char* ws = (char*)d_ws;
    size_t off = 0;
    auto alloc = [&](size_t bytes) -> void* {
        void* p = ws + off;
        off += (bytes + 255) & ~(size_t)255;
        return p;
    };
    // region1: xg [MM,1536] bf16, later reused as xW [MM,1152] bf16
    short* region1 = (short*)alloc((size_t)MM * Dd * 2);
    // region2: x0 [MM,1536] bf16; later xA at +0, xB at +MM*K2p (x0 dead by then)
    short* region2 = (short*)alloc((size_t)MM * Dd * 2);
    short* wlin16  = (short*)alloc((size_t)Dd * Dd * 2);
    short* w0c     = (short*)alloc((size_t)Nc * Dd * 2);
    short* wc123   = (short*)alloc((size_t)3 * Nc * K2p * 2);
    int*   gidx    = (int*)alloc((size_t)MM * 4);
    float* Wc      = (float*)alloc((size_t)(2 * K2p + 2) * 4);

    short* xg = region1;
    short* xW = region1;
    short* x0 = region2;
    short* xA = region2;
    short* xB = region2 + (size_t)MM * K2p;

    auto cdiv = [](int a, int b){ return (a + b - 1) / b; };

    // weight prep
    convert_pad<<<cdiv(Dd * Dd, 256), 256, 0, stream>>>(w_lin, wlin16, Dd, Dd, Dd, Dd);
    convert_pad<<<cdiv(Gp * Dd, 256), 256, 0, stream>>>(w_ih0_f, w0c, Gg, Dd, Gp, Dd);
    convert_pad<<<cdiv(Gp * Dd, 256), 256, 0, stream>>>(w_ih0_b, w0c + (size_t)Gp * Dd, Gg, Dd, Gp, Dd);
    for (int l = 1; l < 4; l++){
        short* wl = wc123 + (size_t)(l - 1) * Nc * K2p;
        convert_pad<<<cdiv(Gp * K2p, 256), 256, 0, stream>>>(w_ih_f + (size_t)(l - 1) * Gg * 282,
                                                             wl, Gg, 282, Gp, K2p);
        convert_pad<<<cdiv(Gp * K2p, 256), 256, 0, stream>>>(w_ih_b + (size_t)(l - 1) * Gg * 282,
                                                             wl + (size_t)Gp * K2p, Gg, 282, Gp, K2p);
    }
    wc_build<<<1, 384, 0, stream>>>(w1, b1, w2, b2, Wc);

    build_gather<<<cdiv(MM, 256), 256, 0, stream>>>(offm, gidx);
    gather_convert<<<cdiv(MM * 192, 256), 256, 0, stream>>>(tok, gidx, xg);

    // lin: x0 = xg @ w_lin^T + b_lin  (empty rows zeroed via gidx)
    gemm128<<<282 * (Dd / 128), 256, 0, stream>>>(xg, wlin16, b_lin, b_lin,
                                                  Dd, 0, Dd, x0, gidx, Dd, Dd / 128, Dd);

    const short* xin = x0;
    int Kl = Dd;
    short* outbuf[4] = { xA, xB, xA, xB };
    for (int l = 0; l < 4; l++){
        const short* wl = (l == 0) ? w0c : wc123 + (size_t)(l - 1) * Nc * K2p;
        gemm128<<<282 * (Nc / 128), 256, 0, stream>>>(xin, wl,
                                                      b_f + (size_t)l * Gg, b_b + (size_t)l * Gg,
                                                      Gg, Gg, Gp, xW, nullptr, Kl, Nc / 128, Nc);
        lstm_scan<<<512, 576, 0, stream>>>(xW,
                                           w_hh_f + (size_t)l * Gg * Hh, w_hh_b + (size_t)l * Gg * Hh,
                                           h0 + (size_t)(2 * l) * Bb * Hh, c0 + (size_t)(2 * l) * Bb * Hh,
                                           outbuf[l],
                                           ohn + (size_t)(2 * l) * Bb * Hh, ocn + (size_t)(2 * l) * Bb * Hh);
        xin = outbuf[l];
        Kl = K2p;
    }

    head2_k<<<cdiv(MM, 256), 256, 0, stream>>>(xB, Wc, oX1, oX2);
}